// Round 11
// baseline (201.218 us; speedup 1.0000x reference)
//
#include <hip/hip_runtime.h>
#include <hip/hip_bf16.h>

typedef unsigned short u16;
typedef __attribute__((ext_vector_type(4))) short bf16x4;
typedef __attribute__((ext_vector_type(8))) short bf16x8;
typedef __attribute__((ext_vector_type(4))) float f32x4;
typedef __attribute__((ext_vector_type(16))) float f32x16;

#define NB_ 4
#define NT_ 2048
#define NC_ 768
#define NH_ 12
#define ND_ 64
#define NM_ (NB_*NT_)   // 8192 rows
#define KC_ 24          // K=768 -> 24 chunks of 32

// 1/sqrt(64) * log2(e): folded into q at the QKV epilogue -> attention runs in exp2 domain
#define SCQ_ 0.18033688011112042f

__device__ __forceinline__ u16 f2bf(float f){
  union { float f; unsigned u; } c; c.f = f;
  unsigned u = c.u;
  return (u16)((u + 0x7fffu + ((u>>16)&1u)) >> 16);  // RNE
}

__device__ __forceinline__ unsigned pkbf(float a, float b){
  __hip_bfloat162 h = __float22bfloat162_rn(make_float2(a,b));  // v_cvt_pk_bf16_f32
  union { __hip_bfloat162 h; unsigned u; } c; c.h = h; return c.u;
}

__device__ __forceinline__ f32x16 mfma32(bf16x8 a, bf16x8 b, f32x16 c){
  return __builtin_amdgcn_mfma_f32_32x32x16_bf16(a, b, c, 0, 0, 0);
}

__device__ __forceinline__ void gload_lds16(const void* g, void* l){
  __builtin_amdgcn_global_load_lds(
    (const __attribute__((address_space(1))) void*)g,
    (__attribute__((address_space(3))) void*)l, 16, 0, 0);
}

// 128-panel blocked layout (GEMM A and B operands):
//   off(row,k) = ((row>>7)*KC_ + (k>>5))*4096 + ((k>>3)&3)*1024 + (row&127)*8 + (k&7)

// ---------------- cast x (f32 -> bf16, blocked), 4 elems/thread ----------------
__global__ __launch_bounds__(256) void cast_f32_bf16_k(
    const float* __restrict__ in, u16* __restrict__ out, int n4){
  int i = blockIdx.x*256 + threadIdx.x;
  if (i >= n4) return;
  float4 v = ((const float4*)in)[i];
  int row = i / (NC_/4), k4 = (i % (NC_/4))*4;
  size_t off = (((size_t)(row>>7)*KC_ + (k4>>5))*4 + ((k4>>3)&3))*1024 + (row&127)*8 + (k4&7);
  bf16x4 o;
  o[0]=(short)f2bf(v.x); o[1]=(short)f2bf(v.y);
  o[2]=(short)f2bf(v.z); o[3]=(short)f2bf(v.w);
  *(bf16x4*)(out + off) = o;
}

// ------------- transpose + cast: in f32 [R=K][Cc=n] -> 128-panel blocked bf16 -------------
__global__ __launch_bounds__(256) void transpose_cast_k(
    const float* __restrict__ in, u16* __restrict__ out, int R, int Cc){
  __shared__ float tile[32][33];
  int tx = threadIdx.x, ty = threadIdx.y;          // 32 x 8
  int c0 = blockIdx.x*32, r0 = blockIdx.y*32;
  #pragma unroll
  for (int j=0;j<32;j+=8) tile[ty+j][tx] = in[(size_t)(r0+ty+j)*Cc + c0+tx];
  __syncthreads();
  #pragma unroll
  for (int j=0;j<32;j+=8){
    int n = c0+ty+j, k = r0+tx;
    size_t off = (((size_t)(n>>7)*KC_ + (k>>5))*4 + ((k>>3)&3))*1024 + (n&127)*8 + (k&7);
    out[off] = f2bf(tile[tx][ty+j]);
  }
}

// ---------------- GEMM: 128x128 block, 4 waves x (64m x 64n), 32x32x16 MFMA -------
// Triple-buffered LDS + counted vmcnt + raw s_barrier: prefetch loads stay in flight
// across barriers (no vmcnt(0) drain in the loop). Both operands in 128-panel blocked
// slot-major layout -> linear gload_lds staging + conflict-free ds_read_b128 frags.
// MODE 0: qkv -> q*scale [B,H,T,D]; k,v slot-major chunked for attn staging
// MODE 1: proj -> f32 out [M][768] + bias
template<int MODE>
__global__ __launch_bounds__(256,3) void gemm128p(
  const u16* __restrict__ A, const u16* __restrict__ BT, const float* __restrict__ bias,
  u16* __restrict__ qo, u16* __restrict__ ko, u16* __restrict__ vo,
  float* __restrict__ fo)
{
  __shared__ u16 lds[3][8192];    // [buf][ A 128x32 | B 128x32 ], 48 KB total
  const int t = threadIdx.x, w = t>>6, l = t&63;
  const int lq = l&31, h = l>>5;
  const int NXB = (MODE==0) ? 18 : 6;
  const int nwg = 64*NXB;
  // bijective XCD swizzle (nwg % 8 == 0): each XCD gets a contiguous tile range
  int sw = (blockIdx.x & 7)*(nwg>>3) + (blockIdx.x >> 3);
  const int rb = sw / NXB, nb = sw % NXB;
  const int brow = rb*128, bcol = nb*128;
  const int wr = (w>>1)*64, wc = (w&1)*64;

  f32x16 acc[2][2];
  #pragma unroll
  for (int i=0;i<2;i++)
    #pragma unroll
    for (int j=0;j<2;j++)
      #pragma unroll
      for (int r=0;r<16;r++) acc[i][j][r] = 0.f;

  auto stage = [&](int buf, int kc){
    const u16* Ag = A  + ((size_t)(rb*KC_ + kc))*4096;
    const u16* Bg = BT + ((size_t)(nb*KC_ + kc))*4096;
    char* La = (char*)&lds[buf][0];
    char* Lb = (char*)&lds[buf][4096];
    #pragma unroll
    for (int it=0; it<2; ++it){
      gload_lds16(Ag + (it*256+t)*8, La + (it*256+t)*16);
      gload_lds16(Bg + (it*256+t)*8, Lb + (it*256+t)*16);
    }
  };

  stage(0,0);
  stage(1,1);
  int cur = 0;
  for (int kc=0; kc<KC_; ++kc){
    // counted wait: tile kc landed (4 loads of kc+1 may stay in flight), then barrier
    if (kc+1 < KC_) asm volatile("s_waitcnt vmcnt(4)\ns_barrier" ::: "memory");
    else            asm volatile("s_waitcnt vmcnt(0)\ns_barrier" ::: "memory");
    if (kc+2 < KC_){ int nb3 = cur+2; if (nb3>=3) nb3-=3; stage(nb3, kc+2); }
    const u16* La = &lds[cur][0];
    const u16* Lb = &lds[cur][4096];
    #pragma unroll
    for (int ks=0; ks<2; ++ks){
      bf16x8 af[2], bfr[2];
      #pragma unroll
      for (int mi=0;mi<2;mi++)
        af[mi]  = *(const bf16x8*)(La + ((2*ks+h)*128 + wr + mi*32 + lq)*8);
      #pragma unroll
      for (int nj=0;nj<2;nj++)
        bfr[nj] = *(const bf16x8*)(Lb + ((2*ks+h)*128 + wc + nj*32 + lq)*8);
      __builtin_amdgcn_s_setprio(1);
      #pragma unroll
      for (int mi=0;mi<2;mi++)
        #pragma unroll
        for (int nj=0;nj<2;nj++)
          acc[mi][nj] = mfma32(af[mi], bfr[nj], acc[mi][nj]);
      __builtin_amdgcn_s_setprio(0);
    }
    if (++cur == 3) cur = 0;
  }

  // C/D map: col(n) = lq, row(m) offset = (r&3) + 8*(r>>2) + 4*h  (r in [0,16))
  if (MODE == 1){
    #pragma unroll
    for (int nj=0;nj<2;nj++){
      int n = bcol + wc + nj*32 + lq;
      float bs = bias[n];
      #pragma unroll
      for (int mi=0;mi<2;mi++)
        #pragma unroll
        for (int r=0;r<16;r++){
          int m = brow + wr + mi*32 + (r&3) + 8*(r>>2) + 4*h;
          fo[(size_t)m*NC_ + n] = acc[mi][nj][r] + bs;
        }
    }
  } else {
    const int sec = nb/6;                  // 6 128-col blocks per q/k/v section
    u16* outp = (sec==0) ? qo : (sec==1 ? ko : vo);
    #pragma unroll
    for (int nj=0;nj<2;nj++){
      int n = bcol + wc + nj*32 + lq;
      int cc = n - sec*NC_;
      int hd = cc >> 6, d = cc & 63;
      float bs = bias[n];
      #pragma unroll
      for (int mi=0;mi<2;mi++)
        #pragma unroll
        for (int r=0;r<16;r++){
          int m = brow + wr + mi*32 + (r&3) + 8*(r>>2) + 4*h;
          int bb = m >> 11, tt = m & 2047;
          float v = acc[mi][nj][r] + bs;
          if (sec == 0) v *= SCQ_;         // pre-scale q for exp2-domain attn
          size_t bhbase = ((size_t)bb*NH_ + hd)*((size_t)NT_*ND_);
          size_t off;
          if (sec == 0){
            off = bhbase + (size_t)tt*ND_ + d;                 // q [B,H,T,D]
          } else if (sec == 1){
            // k slot-major: [chunk=tt>>6][slot=d>>3][row=tt&63][el=d&7]
            off = bhbase + (size_t)(tt>>6)*4096 + (size_t)(d>>3)*512 + (tt&63)*8 + (d&7);
          } else {
            // v^T, kv sigma-permuted within 16-blocks, slot-major over position p
            int p = (tt & ~15) | (h<<3) | (r&3) | (((r>>2)&1)<<2);
            off = bhbase + (size_t)(p>>6)*4096 + (size_t)((p&63)>>3)*512 + d*8 + (p&7);
          }
          outp[off] = f2bf(v);
        }
    }
  }
}

// ---------------- flash attention v11: K-only LDS (24 KB), V direct from L2 -------
// V slot-major chunks are perfectly coalesced (16B/lane) and L2-resident -> load V
// straight to registers; only K is LDS-staged (3 bufs x 8 KB). LDS 48->24 KB lifts
// residency 3 -> 5-6 blocks/CU (the r10 bottleneck: latency-bound at 12 waves/CU).
// Issue order per chunk makes the steady-state barrier stall-free:
//   [wait vmcnt(2); barrier]  (only K(c+2)'s 2 loads may be outstanding)
//   V(c) reg-loads (8x dwordx4) -> stage K(c+2) -> QK (ds_read, K(c) in LDS) ->
//   softmax -> PV (implicit V wait also drains the older K(c+1)).
// 768 static one-shot blocks, heavy-first map, all co-resident (r8 L2 lesson).
// No-max exp2 softmax (r9-verified); P feeds PV in-lane.
__global__ __launch_bounds__(256,4) void attn_kernel(
    const u16* __restrict__ qg, const u16* __restrict__ kg,
    const u16* __restrict__ vg, u16* __restrict__ y)
{
  __shared__ u16 lds[3][4096];    // K only: [buf][chunk 4096 el], 24 KB
  const int t = threadIdx.x, w = t>>6, l = t&63;
  const int lq = l&31, h = l>>5;
  const int bid = blockIdx.x;
  const int qt = 15 - (bid/48);   // heaviest q-tiles first
  const int bh = bid % 48;
  const int bb = bh / NH_, hh = bh % NH_;
  const u16* qp = qg + (size_t)bh*NT_*ND_;
  const u16* kp = kg + (size_t)bh*NT_*ND_;    // slot-major chunked
  const u16* vp = vg + (size_t)bh*ND_*NT_;    // slot-major chunked, kv-permuted
  const int qmin = qt*128 + w*32;
  const int q = qmin + lq;        // this lane's q row (column of S^T)

  // Q frags (pi-permuted): slot i of k-block ks holds Q[q][ks*16 + 8h + i]
  bf16x8 Qf[4];
  {
    const u16* qr = qp + (size_t)q*ND_ + 8*h;
    #pragma unroll
    for (int ks=0; ks<4; ++ks) Qf[ks] = *(const bf16x8*)(qr + ks*16);
  }

  f32x16 o0, o1;                  // O^T acc: col=q, row d=(r&3)+8*(r>>2)+4h (+32 o1)
  float psum[16];                 // running sum of P (this lane's 32 scores/chunk)
  #pragma unroll
  for (int r=0;r<16;r++){ o0[r]=0.f; o1[r]=0.f; psum[r]=0.f; }
  const int nc = 2*qt + 2;        // same for all 4 waves (mask handles the tail)

  auto stage = [&](int buf, int c){
    const u16* kc2 = kp + c*4096;
    #pragma unroll
    for (int it=0; it<2; ++it)
      gload_lds16(kc2 + (it*256 + t)*8, (char*)&lds[buf][0] + (it*256 + t)*16);
  };

  stage(0,0);
  stage(1,1);                     // nc >= 2 always
  int cur = 0;
  for (int c=0; c<nc; ++c){
    // K(c) landed when <=2 loads (K(c+1)'s) remain; steady-state this passes instantly
    asm volatile("s_waitcnt vmcnt(2)\ns_barrier" ::: "memory");

    // V(c) register loads first (oldest after K(c+1)); latency hides under QK+softmax
    const u16* vc = vp + c*4096;
    bf16x8 vf0[4], vf1[4];
    #pragma unroll
    for (int j=0;j<4;j++){
      vf0[j] = *(const bf16x8*)(vc + ((2*j+h)*64      + lq)*8);
      vf1[j] = *(const bf16x8*)(vc + ((2*j+h)*64 + 32 + lq)*8);
    }
    // then stage K(c+2) (youngest -> stays in flight across the next barrier)
    if (c+2 < nc){ int nb3 = cur+2; if (nb3>=3) nb3-=3; stage(nb3, c+2); }

    const u16* Kb = &lds[cur][0];
    const int kv0 = c*64;

    // S^T (64 kv x 32 q), q pre-scaled -> exp2 domain
    f32x16 s0, s1;
    #pragma unroll
    for (int r=0;r<16;r++){ s0[r]=0.f; s1[r]=0.f; }
    __builtin_amdgcn_s_setprio(1);
    #pragma unroll
    for (int ks=0; ks<4; ++ks){
      bf16x8 k0 = *(const bf16x8*)(Kb + ((2*ks+h)*64      + lq)*8);
      bf16x8 k1 = *(const bf16x8*)(Kb + ((2*ks+h)*64 + 32 + lq)*8);
      s0 = mfma32(k0, Qf[ks], s0);
      s1 = mfma32(k1, Qf[ks], s1);
    }
    __builtin_amdgcn_s_setprio(0);

    // causal mask: wave-uniform branch; covers diagonal and fully-masked chunks
    if (kv0 + 63 > qmin){
      #pragma unroll
      for (int r=0;r<16;r++){
        int kva = kv0 + (r&3) + 8*(r>>2) + 4*h;
        s0[r] = (kva      <= q) ? s0[r] : -3e38f;
        s1[r] = (kva + 32 <= q) ? s1[r] : -3e38f;
      }
    }

    // P = exp2(s) (no max subtraction needed; masked -> exp2(-3e38) = 0)
    union { unsigned wd[16]; bf16x8 v[4]; } pf;
    #pragma unroll
    for (int j=0;j<8;j++){
      float a = exp2f(s0[2*j]), b = exp2f(s0[2*j+1]);
      psum[j] += a + b;
      pf.wd[j] = pkbf(a,b);
    }
    #pragma unroll
    for (int j=0;j<8;j++){
      float a = exp2f(s1[2*j]), b = exp2f(s1[2*j+1]);
      psum[8+j] += a + b;
      pf.wd[8+j] = pkbf(a,b);
    }

    // PV: O^T += V^T * P^T ; P regs feed B-operand directly (in-lane);
    // V-reg consumption forces the implicit wait that also drains K(c+1)
    __builtin_amdgcn_s_setprio(1);
    #pragma unroll
    for (int j=0;j<4;j++){
      o0 = mfma32(vf0[j], pf.v[j], o0);
      o1 = mfma32(vf1[j], pf.v[j], o1);
    }
    __builtin_amdgcn_s_setprio(0);
    if (++cur == 3) cur = 0;
  }

  // lsum: tree-reduce psum once, + cross-half partner (other 32 kv of each chunk)
  #pragma unroll
  for (int st=8; st>=1; st>>=1)
    #pragma unroll
    for (int i=0;i<st;i++) psum[i] += psum[i+st];
  float lsum = psum[0] + __shfl_xor(psum[0], 32);
  float inv = 1.f / lsum;

  // epilogue: y in 128-panel blocked layout for proj: row m = bb*NT+q, k = hh*64+d
  const int m = bb*NT_ + q;
  const int rbm = m>>7, rr = m&127;
  #pragma unroll
  for (int db=0; db<2; ++db){
    #pragma unroll
    for (int g2=0; g2<4; ++g2){
      float e0 = (db ? o1[g2*4+0] : o0[g2*4+0]) * inv;
      float e1 = (db ? o1[g2*4+1] : o0[g2*4+1]) * inv;
      float e2 = (db ? o1[g2*4+2] : o0[g2*4+2]) * inv;
      float e3 = (db ? o1[g2*4+3] : o0[g2*4+3]) * inv;
      unsigned w0 = pkbf(e0,e1), w1 = pkbf(e2,e3);
      int k = hh*ND_ + db*32 + g2*8 + 4*h;
      size_t off = (((size_t)rbm*KC_ + (k>>5))*4 + ((k>>3)&3))*1024 + rr*8 + (k&7);
      *(uint2*)(y + off) = make_uint2(w0, w1);
    }
  }
}

// ---------------- launch ----------------
extern "C" void kernel_launch(void* const* d_in, const int* in_sizes, int n_in,
                              void* d_out, int out_size, void* d_ws, size_t ws_size,
                              hipStream_t stream) {
  const float* x  = (const float*)d_in[0];
  const float* wa = (const float*)d_in[1];
  const float* ba = (const float*)d_in[2];
  const float* wp = (const float*)d_in[3];
  const float* bp = (const float*)d_in[4];
  float* out = (float*)d_out;

  char* ws = (char*)d_ws;
  const size_t szXB = (size_t)NM_*NC_*2;        // 12,582,912
  const size_t szWA = (size_t)3*NC_*NC_*2;      //  3,538,944
  const size_t szWP = (size_t)NC_*NC_*2;        //  1,179,648
  const size_t szQ  = szXB;
  u16* xb  = (u16*)(ws);
  u16* wat = (u16*)(ws + szXB);
  u16* wpt = (u16*)(ws + szXB + szWA);
  u16* qb  = (u16*)(ws + szXB + szWA + szWP);
  u16* kb  = (u16*)((char*)qb + szQ);
  u16* vb  = (u16*)((char*)kb + szQ);
  u16* yb  = xb;    // reuse x-slot: attn writes y after qkv GEMM consumed xb

  // 1) casts / transposes into 128-panel blocked layouts
  cast_f32_bf16_k<<<dim3((NM_*NC_/4 + 255)/256), dim3(256), 0, stream>>>(x, xb, NM_*NC_/4);
  transpose_cast_k<<<dim3(3*NC_/32, NC_/32), dim3(32,8), 0, stream>>>(wa, wat, NC_, 3*NC_);
  transpose_cast_k<<<dim3(NC_/32, NC_/32), dim3(32,8), 0, stream>>>(wp, wpt, NC_, NC_);
  // 2) qkv = x @ w_attn + b_attn  -> q*scale, k/v slot-major scattered (1152 blocks)
  gemm128p<0><<<dim3(64*18), dim3(256), 0, stream>>>(xb, wat, ba, qb, kb, vb, (float*)nullptr);
  // 3) flash attention -> y (blocked) bf16; 768 static blocks, all co-resident
  attn_kernel<<<dim3(NB_*NH_*(NT_/128)), dim3(256), 0, stream>>>(qb, kb, vb, yb);
  // 4) out = y @ w_proj + b_proj (f32); 384 blocks, single round
  gemm128p<1><<<dim3(64*6), dim3(256), 0, stream>>>(yb, wpt, bp,
      (u16*)nullptr, (u16*)nullptr, (u16*)nullptr, out);
}

// Round 12
// 132.856 us; speedup vs baseline: 1.5146x; 1.5146x over previous
//
#include <hip/hip_runtime.h>
#include <hip/hip_bf16.h>

typedef unsigned short u16;
typedef __attribute__((ext_vector_type(4))) short bf16x4;
typedef __attribute__((ext_vector_type(8))) short bf16x8;
typedef __attribute__((ext_vector_type(4))) float f32x4;
typedef __attribute__((ext_vector_type(16))) float f32x16;

#define NB_ 4
#define NT_ 2048
#define NC_ 768
#define NH_ 12
#define ND_ 64
#define NM_ (NB_*NT_)   // 8192 rows
#define KC_ 24          // K=768 -> 24 chunks of 32

// 1/sqrt(64) * log2(e): folded into q at the QKV epilogue -> attention runs in exp2 domain
#define SCQ_ 0.18033688011112042f

__device__ __forceinline__ u16 f2bf(float f){
  union { float f; unsigned u; } c; c.f = f;
  unsigned u = c.u;
  return (u16)((u + 0x7fffu + ((u>>16)&1u)) >> 16);  // RNE
}

__device__ __forceinline__ unsigned pkbf(float a, float b){
  __hip_bfloat162 h = __float22bfloat162_rn(make_float2(a,b));  // v_cvt_pk_bf16_f32
  union { __hip_bfloat162 h; unsigned u; } c; c.h = h; return c.u;
}

__device__ __forceinline__ f32x16 mfma32(bf16x8 a, bf16x8 b, f32x16 c){
  return __builtin_amdgcn_mfma_f32_32x32x16_bf16(a, b, c, 0, 0, 0);
}

__device__ __forceinline__ void gload_lds16(const void* g, void* l){
  __builtin_amdgcn_global_load_lds(
    (const __attribute__((address_space(1))) void*)g,
    (__attribute__((address_space(3))) void*)l, 16, 0, 0);
}

// 128-panel blocked layout (GEMM A and B operands):
//   off(row,k) = ((row>>7)*KC_ + (k>>5))*4096 + ((k>>3)&3)*1024 + (row&127)*8 + (k&7)

// ---------------- cast x (f32 -> bf16, blocked), 4 elems/thread ----------------
__global__ __launch_bounds__(256) void cast_f32_bf16_k(
    const float* __restrict__ in, u16* __restrict__ out, int n4){
  int i = blockIdx.x*256 + threadIdx.x;
  if (i >= n4) return;
  float4 v = ((const float4*)in)[i];
  int row = i / (NC_/4), k4 = (i % (NC_/4))*4;
  size_t off = (((size_t)(row>>7)*KC_ + (k4>>5))*4 + ((k4>>3)&3))*1024 + (row&127)*8 + (k4&7);
  bf16x4 o;
  o[0]=(short)f2bf(v.x); o[1]=(short)f2bf(v.y);
  o[2]=(short)f2bf(v.z); o[3]=(short)f2bf(v.w);
  *(bf16x4*)(out + off) = o;
}

// ------------- transpose + cast: in f32 [R=K][Cc=n] -> 128-panel blocked bf16 -------------
__global__ __launch_bounds__(256) void transpose_cast_k(
    const float* __restrict__ in, u16* __restrict__ out, int R, int Cc){
  __shared__ float tile[32][33];
  int tx = threadIdx.x, ty = threadIdx.y;          // 32 x 8
  int c0 = blockIdx.x*32, r0 = blockIdx.y*32;
  #pragma unroll
  for (int j=0;j<32;j+=8) tile[ty+j][tx] = in[(size_t)(r0+ty+j)*Cc + c0+tx];
  __syncthreads();
  #pragma unroll
  for (int j=0;j<32;j+=8){
    int n = c0+ty+j, k = r0+tx;
    size_t off = (((size_t)(n>>7)*KC_ + (k>>5))*4 + ((k>>3)&3))*1024 + (n&127)*8 + (k&7);
    out[off] = f2bf(tile[tx][ty+j]);
  }
}

// ---------------- GEMM: 128x128 block, 4 waves x (64m x 64n), 32x32x16 MFMA -------
// Triple-buffered LDS + counted vmcnt + raw s_barrier: prefetch loads stay in flight
// across barriers (no vmcnt(0) drain in the loop). Both operands in 128-panel blocked
// slot-major layout -> linear gload_lds staging + conflict-free ds_read_b128 frags.
// MODE 0: qkv -> q*scale [B,H,T,D]; k,v slot-major chunked for attn staging
// MODE 1: proj -> f32 out [M][768] + bias
template<int MODE>
__global__ __launch_bounds__(256,3) void gemm128p(
  const u16* __restrict__ A, const u16* __restrict__ BT, const float* __restrict__ bias,
  u16* __restrict__ qo, u16* __restrict__ ko, u16* __restrict__ vo,
  float* __restrict__ fo)
{
  __shared__ u16 lds[3][8192];    // [buf][ A 128x32 | B 128x32 ], 48 KB total
  const int t = threadIdx.x, w = t>>6, l = t&63;
  const int lq = l&31, h = l>>5;
  const int NXB = (MODE==0) ? 18 : 6;
  const int nwg = 64*NXB;
  // bijective XCD swizzle (nwg % 8 == 0): each XCD gets a contiguous tile range
  int sw = (blockIdx.x & 7)*(nwg>>3) + (blockIdx.x >> 3);
  const int rb = sw / NXB, nb = sw % NXB;
  const int brow = rb*128, bcol = nb*128;
  const int wr = (w>>1)*64, wc = (w&1)*64;

  f32x16 acc[2][2];
  #pragma unroll
  for (int i=0;i<2;i++)
    #pragma unroll
    for (int j=0;j<2;j++)
      #pragma unroll
      for (int r=0;r<16;r++) acc[i][j][r] = 0.f;

  auto stage = [&](int buf, int kc){
    const u16* Ag = A  + ((size_t)(rb*KC_ + kc))*4096;
    const u16* Bg = BT + ((size_t)(nb*KC_ + kc))*4096;
    char* La = (char*)&lds[buf][0];
    char* Lb = (char*)&lds[buf][4096];
    #pragma unroll
    for (int it=0; it<2; ++it){
      gload_lds16(Ag + (it*256+t)*8, La + (it*256+t)*16);
      gload_lds16(Bg + (it*256+t)*8, Lb + (it*256+t)*16);
    }
  };

  stage(0,0);
  stage(1,1);
  int cur = 0;
  for (int kc=0; kc<KC_; ++kc){
    // counted wait: tile kc landed (4 loads of kc+1 may stay in flight), then barrier
    if (kc+1 < KC_) asm volatile("s_waitcnt vmcnt(4)\ns_barrier" ::: "memory");
    else            asm volatile("s_waitcnt vmcnt(0)\ns_barrier" ::: "memory");
    if (kc+2 < KC_){ int nb3 = cur+2; if (nb3>=3) nb3-=3; stage(nb3, kc+2); }
    const u16* La = &lds[cur][0];
    const u16* Lb = &lds[cur][4096];
    #pragma unroll
    for (int ks=0; ks<2; ++ks){
      bf16x8 af[2], bfr[2];
      #pragma unroll
      for (int mi=0;mi<2;mi++)
        af[mi]  = *(const bf16x8*)(La + ((2*ks+h)*128 + wr + mi*32 + lq)*8);
      #pragma unroll
      for (int nj=0;nj<2;nj++)
        bfr[nj] = *(const bf16x8*)(Lb + ((2*ks+h)*128 + wc + nj*32 + lq)*8);
      __builtin_amdgcn_s_setprio(1);
      #pragma unroll
      for (int mi=0;mi<2;mi++)
        #pragma unroll
        for (int nj=0;nj<2;nj++)
          acc[mi][nj] = mfma32(af[mi], bfr[nj], acc[mi][nj]);
      __builtin_amdgcn_s_setprio(0);
    }
    if (++cur == 3) cur = 0;
  }

  // C/D map: col(n) = lq, row(m) offset = (r&3) + 8*(r>>2) + 4*h  (r in [0,16))
  if (MODE == 1){
    #pragma unroll
    for (int nj=0;nj<2;nj++){
      int n = bcol + wc + nj*32 + lq;
      float bs = bias[n];
      #pragma unroll
      for (int mi=0;mi<2;mi++)
        #pragma unroll
        for (int r=0;r<16;r++){
          int m = brow + wr + mi*32 + (r&3) + 8*(r>>2) + 4*h;
          fo[(size_t)m*NC_ + n] = acc[mi][nj][r] + bs;
        }
    }
  } else {
    const int sec = nb/6;                  // 6 128-col blocks per q/k/v section
    u16* outp = (sec==0) ? qo : (sec==1 ? ko : vo);
    #pragma unroll
    for (int nj=0;nj<2;nj++){
      int n = bcol + wc + nj*32 + lq;
      int cc = n - sec*NC_;
      int hd = cc >> 6, d = cc & 63;
      float bs = bias[n];
      #pragma unroll
      for (int mi=0;mi<2;mi++)
        #pragma unroll
        for (int r=0;r<16;r++){
          int m = brow + wr + mi*32 + (r&3) + 8*(r>>2) + 4*h;
          int bb = m >> 11, tt = m & 2047;
          float v = acc[mi][nj][r] + bs;
          if (sec == 0) v *= SCQ_;         // pre-scale q for exp2-domain attn
          size_t bhbase = ((size_t)bb*NH_ + hd)*((size_t)NT_*ND_);
          size_t off;
          if (sec == 0){
            off = bhbase + (size_t)tt*ND_ + d;                 // q [B,H,T,D]
          } else if (sec == 1){
            // k slot-major: [chunk=tt>>6][slot=d>>3][row=tt&63][el=d&7]
            off = bhbase + (size_t)(tt>>6)*4096 + (size_t)(d>>3)*512 + (tt&63)*8 + (d&7);
          } else {
            // v^T, kv sigma-permuted within 16-blocks, slot-major over position p
            int p = (tt & ~15) | (h<<3) | (r&3) | (((r>>2)&1)<<2);
            off = bhbase + (size_t)(p>>6)*4096 + (size_t)((p&63)>>3)*512 + d*8 + (p&7);
          }
          outp[off] = f2bf(v);
        }
    }
  }
}

// ---------------- flash attention v12: 2-buf LDS, TOP-placed no-drain barrier -------
// K AND V staged in LDS (r11 lesson: V-direct duplicates V 4x across waves -> L2-BW
// bound). 2 buffers (32 KB) -> 4 blocks/CU, 16 waves. The barrier is at the TOP of
// the loop as "s_waitcnt vmcnt(0); s_barrier", and stage(c+1) is issued AFTER it:
// the vmcnt(0) waits only on stage(c), issued one full iteration (~2000 cyc) earlier
// -> free in steady state; the just-issued stage(c+1) is never drained (crosses the
// NEXT barrier young). Correctness: top barrier orders all waves' reads of
// buf[cur^1] (iter c-1) before stage(c+1) overwrites it; own-vmcnt(0)+barrier
// guarantees every wave's stage(c) landed before any ds_read of buf[cur].
// 768 static one-shot blocks, heavy-first map, all co-resident (r8 L2 lesson);
// slot-major staging (conflict-free); no-max exp2 softmax; P feeds PV in-lane.
__global__ __launch_bounds__(256,4) void attn_kernel(
    const u16* __restrict__ qg, const u16* __restrict__ kg,
    const u16* __restrict__ vg, u16* __restrict__ y)
{
  __shared__ u16 lds[2][8192];    // [buf][ K 4096 el | V 4096 el ], 32 KB
  const int t = threadIdx.x, w = t>>6, l = t&63;
  const int lq = l&31, h = l>>5;
  const int bid = blockIdx.x;
  const int qt = 15 - (bid/48);   // heaviest q-tiles first
  const int bh = bid % 48;
  const int bb = bh / NH_, hh = bh % NH_;
  const u16* qp = qg + (size_t)bh*NT_*ND_;
  const u16* kp = kg + (size_t)bh*NT_*ND_;    // slot-major chunked
  const u16* vp = vg + (size_t)bh*ND_*NT_;    // slot-major chunked, kv-permuted
  const int qmin = qt*128 + w*32;
  const int q = qmin + lq;        // this lane's q row (column of S^T)

  // Q frags (pi-permuted): slot i of k-block ks holds Q[q][ks*16 + 8h + i]
  bf16x8 Qf[4];
  {
    const u16* qr = qp + (size_t)q*ND_ + 8*h;
    #pragma unroll
    for (int ks=0; ks<4; ++ks) Qf[ks] = *(const bf16x8*)(qr + ks*16);
  }

  f32x16 o0, o1;                  // O^T acc: col=q, row d=(r&3)+8*(r>>2)+4h (+32 o1)
  float psum[16];                 // running sum of P (this lane's 32 scores/chunk)
  #pragma unroll
  for (int r=0;r<16;r++){ o0[r]=0.f; o1[r]=0.f; psum[r]=0.f; }
  const int nc = 2*qt + 2;        // same for all 4 waves (mask handles the tail)

  auto stage = [&](int buf, int c){
    const u16* kc2 = kp + c*4096;
    const u16* vc2 = vp + c*4096;
    #pragma unroll
    for (int it=0; it<2; ++it){
      gload_lds16(kc2 + (it*256 + t)*8, (char*)&lds[buf][0]    + (it*256 + t)*16);
      gload_lds16(vc2 + (it*256 + t)*8, (char*)&lds[buf][4096] + (it*256 + t)*16);
    }
  };

  stage(0,0);
  int cur = 0;
  for (int c=0; c<nc; ++c){
    // waits only on stage(c) (one iteration old -> landed); stage(c+1) issued after
    asm volatile("s_waitcnt vmcnt(0)\ns_barrier" ::: "memory");
    if (c+1 < nc) stage(cur^1, c+1);

    const u16* Kb = &lds[cur][0];
    const u16* Vb = &lds[cur][4096];
    const int kv0 = c*64;

    // S^T (64 kv x 32 q), q pre-scaled -> exp2 domain
    f32x16 s0, s1;
    #pragma unroll
    for (int r=0;r<16;r++){ s0[r]=0.f; s1[r]=0.f; }
    __builtin_amdgcn_s_setprio(1);
    #pragma unroll
    for (int ks=0; ks<4; ++ks){
      bf16x8 k0 = *(const bf16x8*)(Kb + ((2*ks+h)*64      + lq)*8);
      bf16x8 k1 = *(const bf16x8*)(Kb + ((2*ks+h)*64 + 32 + lq)*8);
      s0 = mfma32(k0, Qf[ks], s0);
      s1 = mfma32(k1, Qf[ks], s1);
    }
    __builtin_amdgcn_s_setprio(0);

    // causal mask: wave-uniform branch; covers diagonal and fully-masked chunks
    if (kv0 + 63 > qmin){
      #pragma unroll
      for (int r=0;r<16;r++){
        int kva = kv0 + (r&3) + 8*(r>>2) + 4*h;
        s0[r] = (kva      <= q) ? s0[r] : -3e38f;
        s1[r] = (kva + 32 <= q) ? s1[r] : -3e38f;
      }
    }

    // P = exp2(s) (no max subtraction needed; masked -> exp2(-3e38) = 0)
    union { unsigned wd[16]; bf16x8 v[4]; } pf;
    #pragma unroll
    for (int j=0;j<8;j++){
      float a = exp2f(s0[2*j]), b = exp2f(s0[2*j+1]);
      psum[j] += a + b;
      pf.wd[j] = pkbf(a,b);
    }
    #pragma unroll
    for (int j=0;j<8;j++){
      float a = exp2f(s1[2*j]), b = exp2f(s1[2*j+1]);
      psum[8+j] += a + b;
      pf.wd[8+j] = pkbf(a,b);
    }

    // PV: O^T += V^T * P^T ; P regs feed B-operand directly (in-lane)
    __builtin_amdgcn_s_setprio(1);
    #pragma unroll
    for (int j=0;j<4;j++){
      bf16x8 v0 = *(const bf16x8*)(Vb + ((2*j+h)*64      + lq)*8);
      bf16x8 v1 = *(const bf16x8*)(Vb + ((2*j+h)*64 + 32 + lq)*8);
      o0 = mfma32(v0, pf.v[j], o0);
      o1 = mfma32(v1, pf.v[j], o1);
    }
    __builtin_amdgcn_s_setprio(0);
    cur ^= 1;
  }

  // lsum: tree-reduce psum once, + cross-half partner (other 32 kv of each chunk)
  #pragma unroll
  for (int st=8; st>=1; st>>=1)
    #pragma unroll
    for (int i=0;i<st;i++) psum[i] += psum[i+st];
  float lsum = psum[0] + __shfl_xor(psum[0], 32);
  float inv = 1.f / lsum;

  // epilogue: y in 128-panel blocked layout for proj: row m = bb*NT+q, k = hh*64+d
  const int m = bb*NT_ + q;
  const int rbm = m>>7, rr = m&127;
  #pragma unroll
  for (int db=0; db<2; ++db){
    #pragma unroll
    for (int g2=0; g2<4; ++g2){
      float e0 = (db ? o1[g2*4+0] : o0[g2*4+0]) * inv;
      float e1 = (db ? o1[g2*4+1] : o0[g2*4+1]) * inv;
      float e2 = (db ? o1[g2*4+2] : o0[g2*4+2]) * inv;
      float e3 = (db ? o1[g2*4+3] : o0[g2*4+3]) * inv;
      unsigned w0 = pkbf(e0,e1), w1 = pkbf(e2,e3);
      int k = hh*ND_ + db*32 + g2*8 + 4*h;
      size_t off = (((size_t)rbm*KC_ + (k>>5))*4 + ((k>>3)&3))*1024 + rr*8 + (k&7);
      *(uint2*)(y + off) = make_uint2(w0, w1);
    }
  }
}

// ---------------- launch ----------------
extern "C" void kernel_launch(void* const* d_in, const int* in_sizes, int n_in,
                              void* d_out, int out_size, void* d_ws, size_t ws_size,
                              hipStream_t stream) {
  const float* x  = (const float*)d_in[0];
  const float* wa = (const float*)d_in[1];
  const float* ba = (const float*)d_in[2];
  const float* wp = (const float*)d_in[3];
  const float* bp = (const float*)d_in[4];
  float* out = (float*)d_out;

  char* ws = (char*)d_ws;
  const size_t szXB = (size_t)NM_*NC_*2;        // 12,582,912
  const size_t szWA = (size_t)3*NC_*NC_*2;      //  3,538,944
  const size_t szWP = (size_t)NC_*NC_*2;        //  1,179,648
  const size_t szQ  = szXB;
  u16* xb  = (u16*)(ws);
  u16* wat = (u16*)(ws + szXB);
  u16* wpt = (u16*)(ws + szXB + szWA);
  u16* qb  = (u16*)(ws + szXB + szWA + szWP);
  u16* kb  = (u16*)((char*)qb + szQ);
  u16* vb  = (u16*)((char*)kb + szQ);
  u16* yb  = xb;    // reuse x-slot: attn writes y after qkv GEMM consumed xb

  // 1) casts / transposes into 128-panel blocked layouts
  cast_f32_bf16_k<<<dim3((NM_*NC_/4 + 255)/256), dim3(256), 0, stream>>>(x, xb, NM_*NC_/4);
  transpose_cast_k<<<dim3(3*NC_/32, NC_/32), dim3(32,8), 0, stream>>>(wa, wat, NC_, 3*NC_);
  transpose_cast_k<<<dim3(NC_/32, NC_/32), dim3(32,8), 0, stream>>>(wp, wpt, NC_, NC_);
  // 2) qkv = x @ w_attn + b_attn  -> q*scale, k/v slot-major scattered (1152 blocks)
  gemm128p<0><<<dim3(64*18), dim3(256), 0, stream>>>(xb, wat, ba, qb, kb, vb, (float*)nullptr);
  // 3) flash attention -> y (blocked) bf16; 768 static blocks, all co-resident
  attn_kernel<<<dim3(NB_*NH_*(NT_/128)), dim3(256), 0, stream>>>(qb, kb, vb, yb);
  // 4) out = y @ w_proj + b_proj (f32); 384 blocks, single round
  gemm128p<1><<<dim3(64*6), dim3(256), 0, stream>>>(yb, wpt, bp,
      (u16*)nullptr, (u16*)nullptr, (u16*)nullptr, out);
}

// Round 13
// 131.800 us; speedup vs baseline: 1.5267x; 1.0080x over previous
//
#include <hip/hip_runtime.h>
#include <hip/hip_bf16.h>

typedef unsigned short u16;
typedef __attribute__((ext_vector_type(4))) short bf16x4;
typedef __attribute__((ext_vector_type(8))) short bf16x8;
typedef __attribute__((ext_vector_type(16))) float f32x16;

#define NB_ 4
#define NT_ 2048
#define NC_ 768
#define NH_ 12
#define ND_ 64
#define NM_ (NB_*NT_)   // 8192 rows
#define KC_ 24          // K=768 -> 24 chunks of 32

// 1/sqrt(64) * log2(e): folded into q at the QKV epilogue -> attention runs in exp2 domain
#define SCQ_ 0.18033688011112042f

__device__ __forceinline__ u16 f2bf(float f){
  union { float f; unsigned u; } c; c.f = f;
  unsigned u = c.u;
  return (u16)((u + 0x7fffu + ((u>>16)&1u)) >> 16);  // RNE
}

__device__ __forceinline__ unsigned pkbf(float a, float b){
  __hip_bfloat162 h = __float22bfloat162_rn(make_float2(a,b));  // v_cvt_pk_bf16_f32
  union { __hip_bfloat162 h; unsigned u; } c; c.h = h; return c.u;
}

__device__ __forceinline__ f32x16 mfma32(bf16x8 a, bf16x8 b, f32x16 c){
  return __builtin_amdgcn_mfma_f32_32x32x16_bf16(a, b, c, 0, 0, 0);
}

__device__ __forceinline__ void gload_lds16(const void* g, void* l){
  __builtin_amdgcn_global_load_lds(
    (const __attribute__((address_space(1))) void*)g,
    (__attribute__((address_space(3))) void*)l, 16, 0, 0);
}

// PAN-panel blocked layout (GEMM operands):
//   off(row,k) = ((row/PAN)*KC_ + (k>>5))*(PAN*32) + ((k>>3)&3)*(PAN*8) + (row%PAN)*8 + (k&7)
// x, y, wp use PAN=128; wa uses PAN=96 (gemmQ's 96-col n-tiles).

// ---------------- cast x (f32 -> bf16, 128-panel blocked), 4 elems/thread ----------------
__global__ __launch_bounds__(256) void cast_f32_bf16_k(
    const float* __restrict__ in, u16* __restrict__ out, int n4){
  int i = blockIdx.x*256 + threadIdx.x;
  if (i >= n4) return;
  float4 v = ((const float4*)in)[i];
  int row = i / (NC_/4), k4 = (i % (NC_/4))*4;
  size_t off = (((size_t)(row>>7)*KC_ + (k4>>5))*4 + ((k4>>3)&3))*1024 + (row&127)*8 + (k4&7);
  bf16x4 o;
  o[0]=(short)f2bf(v.x); o[1]=(short)f2bf(v.y);
  o[2]=(short)f2bf(v.z); o[3]=(short)f2bf(v.w);
  *(bf16x4*)(out + off) = o;
}

// ------------- transpose + cast: in f32 [R=K][Cc=n] -> PAN-panel blocked bf16 -------------
template<int PAN>
__global__ __launch_bounds__(256) void transpose_cast_k(
    const float* __restrict__ in, u16* __restrict__ out, int R, int Cc){
  __shared__ float tile[32][33];
  int tx = threadIdx.x, ty = threadIdx.y;          // 32 x 8
  int c0 = blockIdx.x*32, r0 = blockIdx.y*32;
  #pragma unroll
  for (int j=0;j<32;j+=8) tile[ty+j][tx] = in[(size_t)(r0+ty+j)*Cc + c0+tx];
  __syncthreads();
  #pragma unroll
  for (int j=0;j<32;j+=8){
    int n = c0+ty+j, k = r0+tx;
    size_t off = ((size_t)(n/PAN)*KC_ + (k>>5))*(PAN*32)
               + (size_t)((k>>3)&3)*(PAN*8) + (n%PAN)*8 + (k&7);
    out[off] = f2bf(tile[tx][ty+j]);
  }
}

// ---------------- gemmQ: qkv GEMM, 256x96 block, 4 waves x (64m x 96n) ----------------
// 768 blocks = EXACTLY 3/CU x 256 -> all co-resident, zero tail. 2-buf top-barrier
// (v12 pattern): "s_waitcnt vmcnt(0); s_barrier" waits only on the stage issued one
// full iteration earlier (free); the just-issued stage crosses the next barrier young.
// A = x (128-panels, 2 per block); B = wa (96-panels). Linear gload_lds staging,
// conflict-free ds_read_b128 frags (pi-permuted k). Scatters q*scale / k / v(sigma).
__global__ __launch_bounds__(256,3) void gemmQ(
  const u16* __restrict__ A, const u16* __restrict__ BT, const float* __restrict__ bias,
  u16* __restrict__ qo, u16* __restrict__ ko, u16* __restrict__ vo)
{
  __shared__ u16 lds[2][11264];   // [buf][ A-pan0 4096 | A-pan1 4096 | B 3072 ], 44 KB
  const int t = threadIdx.x, w = t>>6, l = t&63;
  const int lq = l&31, h = l>>5;
  // bijective XCD swizzle (768 % 8 == 0)
  int sw = (blockIdx.x & 7)*96 + (blockIdx.x >> 3);
  const int rb = sw / 24, nb = sw % 24;       // 32 rb x 24 nb
  const int brow = rb*256, bcol = nb*96;

  f32x16 acc[2][3];
  #pragma unroll
  for (int i=0;i<2;i++)
    #pragma unroll
    for (int j=0;j<3;j++)
      #pragma unroll
      for (int r=0;r<16;r++) acc[i][j][r] = 0.f;

  auto stage = [&](int buf, int kc){
    const u16* A0 = A  + ((size_t)((rb*2  )*KC_ + kc))*4096;
    const u16* A1 = A  + ((size_t)((rb*2+1)*KC_ + kc))*4096;
    const u16* Bg = BT + ((size_t)(nb*KC_ + kc))*3072;
    char* L = (char*)&lds[buf][0];
    gload_lds16(A0 + t*8,         L + t*16);
    gload_lds16(A0 + (256+t)*8,   L + (256+t)*16);
    gload_lds16(A1 + t*8,         L + 8192  + t*16);
    gload_lds16(A1 + (256+t)*8,   L + 8192  + (256+t)*16);
    gload_lds16(Bg + t*8,         L + 16384 + t*16);
    if (t < 128)
      gload_lds16(Bg + (256+t)*8, L + 16384 + (256+t)*16);
  };

  stage(0,0);
  int cur = 0;
  for (int kc=0; kc<KC_; ++kc){
    // waits only on stage(kc) (one iteration old -> landed); stage(kc+1) issued after
    asm volatile("s_waitcnt vmcnt(0)\ns_barrier" ::: "memory");
    if (kc+1 < KC_) stage(cur^1, kc+1);
    const u16* La = &lds[cur][(w>>1)*4096];   // this wave's A panel
    const u16* Lb = &lds[cur][8192];
    #pragma unroll
    for (int ks=0; ks<2; ++ks){
      bf16x8 af[2], bfr[3];
      #pragma unroll
      for (int mi=0;mi<2;mi++)
        af[mi]  = *(const bf16x8*)(La + ((2*ks+h)*128 + (w&1)*64 + mi*32 + lq)*8);
      #pragma unroll
      for (int nj=0;nj<3;nj++)
        bfr[nj] = *(const bf16x8*)(Lb + ((2*ks+h)*96 + nj*32 + lq)*8);
      __builtin_amdgcn_s_setprio(1);
      #pragma unroll
      for (int mi=0;mi<2;mi++)
        #pragma unroll
        for (int nj=0;nj<3;nj++)
          acc[mi][nj] = mfma32(af[mi], bfr[nj], acc[mi][nj]);
      __builtin_amdgcn_s_setprio(0);
    }
    cur ^= 1;
  }

  // C/D map: col(n) = lq, row(m) offset = (r&3) + 8*(r>>2) + 4*h
  const int sec = nb >> 3;                    // 8 x 96-col blocks per q/k/v section
  u16* outp = (sec==0) ? qo : (sec==1 ? ko : vo);
  #pragma unroll
  for (int nj=0;nj<3;nj++){
    int n = bcol + nj*32 + lq;
    int cc = n - sec*NC_;
    int hd = cc >> 6, d = cc & 63;
    float bs = bias[n];
    #pragma unroll
    for (int mi=0;mi<2;mi++)
      #pragma unroll
      for (int r=0;r<16;r++){
        int m = brow + w*64 + mi*32 + (r&3) + 8*(r>>2) + 4*h;
        int bb = m >> 11, tt = m & 2047;
        float v = acc[mi][nj][r] + bs;
        if (sec == 0) v *= SCQ_;              // pre-scale q for exp2-domain attn
        size_t bhbase = ((size_t)bb*NH_ + hd)*((size_t)NT_*ND_);
        size_t off;
        if (sec == 0){
          off = bhbase + (size_t)tt*ND_ + d;                 // q [B,H,T,D]
        } else if (sec == 1){
          // k slot-major: [chunk=tt>>6][slot=d>>3][row=tt&63][el=d&7]
          off = bhbase + (size_t)(tt>>6)*4096 + (size_t)(d>>3)*512 + (tt&63)*8 + (d&7);
        } else {
          // v^T, kv sigma-permuted within 16-blocks, slot-major over position p
          int p = (tt & ~15) | (h<<3) | (r&3) | (((r>>2)&1)<<2);
          off = bhbase + (size_t)(p>>6)*4096 + (size_t)((p&63)>>3)*512 + d*8 + (p&7);
        }
        outp[off] = f2bf(v);
      }
  }
}

// ---------------- gemmP: proj GEMM, 128x128 block, 2-buf top-barrier ----------------
// 384 blocks at 4 blocks/CU (32 KB LDS) -> all co-resident. f32 out + bias.
__global__ __launch_bounds__(256,4) void gemmP(
  const u16* __restrict__ A, const u16* __restrict__ BT, const float* __restrict__ bias,
  float* __restrict__ fo)
{
  __shared__ u16 lds[2][8192];    // [buf][ A 128x32 | B 128x32 ], 32 KB
  const int t = threadIdx.x, w = t>>6, l = t&63;
  const int lq = l&31, h = l>>5;
  int sw = (blockIdx.x & 7)*48 + (blockIdx.x >> 3);   // 384 % 8 == 0
  const int rb = sw / 6, nb = sw % 6;
  const int brow = rb*128, bcol = nb*128;
  const int wr = (w>>1)*64, wc = (w&1)*64;

  f32x16 acc[2][2];
  #pragma unroll
  for (int i=0;i<2;i++)
    #pragma unroll
    for (int j=0;j<2;j++)
      #pragma unroll
      for (int r=0;r<16;r++) acc[i][j][r] = 0.f;

  auto stage = [&](int buf, int kc){
    const u16* Ag = A  + ((size_t)(rb*KC_ + kc))*4096;
    const u16* Bg = BT + ((size_t)(nb*KC_ + kc))*4096;
    char* La = (char*)&lds[buf][0];
    char* Lb = (char*)&lds[buf][4096];
    #pragma unroll
    for (int it=0; it<2; ++it){
      gload_lds16(Ag + (it*256+t)*8, La + (it*256+t)*16);
      gload_lds16(Bg + (it*256+t)*8, Lb + (it*256+t)*16);
    }
  };

  stage(0,0);
  int cur = 0;
  for (int kc=0; kc<KC_; ++kc){
    asm volatile("s_waitcnt vmcnt(0)\ns_barrier" ::: "memory");
    if (kc+1 < KC_) stage(cur^1, kc+1);
    const u16* La = &lds[cur][0];
    const u16* Lb = &lds[cur][4096];
    #pragma unroll
    for (int ks=0; ks<2; ++ks){
      bf16x8 af[2], bfr[2];
      #pragma unroll
      for (int mi=0;mi<2;mi++)
        af[mi]  = *(const bf16x8*)(La + ((2*ks+h)*128 + wr + mi*32 + lq)*8);
      #pragma unroll
      for (int nj=0;nj<2;nj++)
        bfr[nj] = *(const bf16x8*)(Lb + ((2*ks+h)*128 + wc + nj*32 + lq)*8);
      __builtin_amdgcn_s_setprio(1);
      #pragma unroll
      for (int mi=0;mi<2;mi++)
        #pragma unroll
        for (int nj=0;nj<2;nj++)
          acc[mi][nj] = mfma32(af[mi], bfr[nj], acc[mi][nj]);
      __builtin_amdgcn_s_setprio(0);
    }
    cur ^= 1;
  }

  #pragma unroll
  for (int nj=0;nj<2;nj++){
    int n = bcol + wc + nj*32 + lq;
    float bs = bias[n];
    #pragma unroll
    for (int mi=0;mi<2;mi++)
      #pragma unroll
      for (int r=0;r<16;r++){
        int m = brow + wr + mi*32 + (r&3) + 8*(r>>2) + 4*h;
        fo[(size_t)m*NC_ + n] = acc[mi][nj][r] + bs;
      }
  }
}

// ---------------- flash attention v13: ones-MFMA lsum + masked-chunk skip ----------
// v12 base (2-buf 32 KB top-barrier, 768 static co-resident blocks, heavy-first,
// slot-major conflict-free staging, no-max exp2 softmax, P feeds PV in-lane).
// New: lsum via ls = mfma32(ones, pf.v[j], ls) -- the MFMA sums P over ALL k-lanes
// (both halves), so lsum = ls[0] with zero VALU adds, no tree, no shfl. Fully-masked
// chunks (waves 0,1's last) skip all compute but keep stage+barrier.
__global__ __launch_bounds__(256,4) void attn_kernel(
    const u16* __restrict__ qg, const u16* __restrict__ kg,
    const u16* __restrict__ vg, u16* __restrict__ y)
{
  __shared__ u16 lds[2][8192];    // [buf][ K 4096 el | V 4096 el ], 32 KB
  const int t = threadIdx.x, w = t>>6, l = t&63;
  const int lq = l&31, h = l>>5;
  const int bid = blockIdx.x;
  const int qt = 15 - (bid/48);   // heaviest q-tiles first
  const int bh = bid % 48;
  const int bb = bh / NH_, hh = bh % NH_;
  const u16* qp = qg + (size_t)bh*NT_*ND_;
  const u16* kp = kg + (size_t)bh*NT_*ND_;    // slot-major chunked
  const u16* vp = vg + (size_t)bh*ND_*NT_;    // slot-major chunked, kv-permuted
  const int qmin = qt*128 + w*32;
  const int q = qmin + lq;        // this lane's q row (column of S^T)

  // Q frags (pi-permuted): slot i of k-block ks holds Q[q][ks*16 + 8h + i]
  bf16x8 Qf[4];
  {
    const u16* qr = qp + (size_t)q*ND_ + 8*h;
    #pragma unroll
    for (int ks=0; ks<4; ++ks) Qf[ks] = *(const bf16x8*)(qr + ks*16);
  }
  bf16x8 ones;
  #pragma unroll
  for (int i=0;i<8;i++) ones[i] = (short)0x3F80;   // bf16 1.0

  f32x16 o0, o1, ls;              // O^T acc + lsum acc (all ls rows identical)
  #pragma unroll
  for (int r=0;r<16;r++){ o0[r]=0.f; o1[r]=0.f; ls[r]=0.f; }
  const int nc = 2*qt + 2;        // same for all 4 waves (skip handles the tail)

  auto stage = [&](int buf, int c){
    const u16* kc2 = kp + c*4096;
    const u16* vc2 = vp + c*4096;
    #pragma unroll
    for (int it=0; it<2; ++it){
      gload_lds16(kc2 + (it*256 + t)*8, (char*)&lds[buf][0]    + (it*256 + t)*16);
      gload_lds16(vc2 + (it*256 + t)*8, (char*)&lds[buf][4096] + (it*256 + t)*16);
    }
  };

  stage(0,0);
  int cur = 0;
  for (int c=0; c<nc; ++c){
    // waits only on stage(c) (one iteration old -> landed); stage(c+1) issued after
    asm volatile("s_waitcnt vmcnt(0)\ns_barrier" ::: "memory");
    if (c+1 < nc) stage(cur^1, c+1);

    const int kv0 = c*64;
    if (kv0 <= qmin + 31){        // wave-uniform: skip fully-masked chunks
      const u16* Kb = &lds[cur][0];
      const u16* Vb = &lds[cur][4096];

      // S^T (64 kv x 32 q), q pre-scaled -> exp2 domain
      f32x16 s0, s1;
      #pragma unroll
      for (int r=0;r<16;r++){ s0[r]=0.f; s1[r]=0.f; }
      __builtin_amdgcn_s_setprio(1);
      #pragma unroll
      for (int ks=0; ks<4; ++ks){
        bf16x8 k0 = *(const bf16x8*)(Kb + ((2*ks+h)*64      + lq)*8);
        bf16x8 k1 = *(const bf16x8*)(Kb + ((2*ks+h)*64 + 32 + lq)*8);
        s0 = mfma32(k0, Qf[ks], s0);
        s1 = mfma32(k1, Qf[ks], s1);
      }
      __builtin_amdgcn_s_setprio(0);

      // causal mask: wave-uniform branch; diagonal chunks only
      if (kv0 + 63 > qmin){
        #pragma unroll
        for (int r=0;r<16;r++){
          int kva = kv0 + (r&3) + 8*(r>>2) + 4*h;
          s0[r] = (kva      <= q) ? s0[r] : -3e38f;
          s1[r] = (kva + 32 <= q) ? s1[r] : -3e38f;
        }
      }

      // P = exp2(s); pack pairs (masked -> exp2(-3e38) = 0)
      union { unsigned wd[16]; bf16x8 v[4]; } pf;
      #pragma unroll
      for (int j=0;j<8;j++)
        pf.wd[j]   = pkbf(exp2f(s0[2*j]), exp2f(s0[2*j+1]));
      #pragma unroll
      for (int j=0;j<8;j++)
        pf.wd[8+j] = pkbf(exp2f(s1[2*j]), exp2f(s1[2*j+1]));

      // PV + lsum: O^T += V^T * P^T ; ls += ones * P^T (row sum of P per q)
      __builtin_amdgcn_s_setprio(1);
      #pragma unroll
      for (int j=0;j<4;j++){
        bf16x8 v0 = *(const bf16x8*)(Vb + ((2*j+h)*64      + lq)*8);
        bf16x8 v1 = *(const bf16x8*)(Vb + ((2*j+h)*64 + 32 + lq)*8);
        o0 = mfma32(v0, pf.v[j], o0);
        o1 = mfma32(v1, pf.v[j], o1);
        ls = mfma32(ones, pf.v[j], ls);
      }
      __builtin_amdgcn_s_setprio(0);
    }
    cur ^= 1;
  }

  float inv = 1.f / ls[0];        // all ls elements equal the full kv-sum for q=lq

  // epilogue: y in 128-panel blocked layout for proj: row m = bb*NT+q, k = hh*64+d
  const int m = bb*NT_ + q;
  const int rbm = m>>7, rr = m&127;
  #pragma unroll
  for (int db=0; db<2; ++db){
    #pragma unroll
    for (int g2=0; g2<4; ++g2){
      float e0 = (db ? o1[g2*4+0] : o0[g2*4+0]) * inv;
      float e1 = (db ? o1[g2*4+1] : o0[g2*4+1]) * inv;
      float e2 = (db ? o1[g2*4+2] : o0[g2*4+2]) * inv;
      float e3 = (db ? o1[g2*4+3] : o0[g2*4+3]) * inv;
      unsigned w0 = pkbf(e0,e1), w1 = pkbf(e2,e3);
      int k = hh*ND_ + db*32 + g2*8 + 4*h;
      size_t off = (((size_t)rbm*KC_ + (k>>5))*4 + ((k>>3)&3))*1024 + rr*8 + (k&7);
      *(uint2*)(y + off) = make_uint2(w0, w1);
    }
  }
}

// ---------------- launch ----------------
extern "C" void kernel_launch(void* const* d_in, const int* in_sizes, int n_in,
                              void* d_out, int out_size, void* d_ws, size_t ws_size,
                              hipStream_t stream) {
  const float* x  = (const float*)d_in[0];
  const float* wa = (const float*)d_in[1];
  const float* ba = (const float*)d_in[2];
  const float* wp = (const float*)d_in[3];
  const float* bp = (const float*)d_in[4];
  float* out = (float*)d_out;

  char* ws = (char*)d_ws;
  const size_t szXB = (size_t)NM_*NC_*2;        // 12,582,912
  const size_t szWA = (size_t)3*NC_*NC_*2;      //  3,538,944
  const size_t szWP = (size_t)NC_*NC_*2;        //  1,179,648
  const size_t szQ  = szXB;
  u16* xb  = (u16*)(ws);
  u16* wat = (u16*)(ws + szXB);
  u16* wpt = (u16*)(ws + szXB + szWA);
  u16* qb  = (u16*)(ws + szXB + szWA + szWP);
  u16* kb  = (u16*)((char*)qb + szQ);
  u16* vb  = (u16*)((char*)kb + szQ);
  u16* yb  = xb;    // reuse x-slot: attn writes y after qkv GEMM consumed xb

  // 1) casts / transposes into blocked layouts (x,y,wp: 128-panels; wa: 96-panels)
  cast_f32_bf16_k<<<dim3((NM_*NC_/4 + 255)/256), dim3(256), 0, stream>>>(x, xb, NM_*NC_/4);
  transpose_cast_k<96><<<dim3(3*NC_/32, NC_/32), dim3(32,8), 0, stream>>>(wa, wat, NC_, 3*NC_);
  transpose_cast_k<128><<<dim3(NC_/32, NC_/32), dim3(32,8), 0, stream>>>(wp, wpt, NC_, NC_);
  // 2) qkv = x @ w_attn + b_attn  -> q*scale, k/v slot-major scattered (768 blocks, all resident)
  gemmQ<<<dim3(768), dim3(256), 0, stream>>>(xb, wat, ba, qb, kb, vb);
  // 3) flash attention -> y (blocked) bf16; 768 static blocks, all co-resident
  attn_kernel<<<dim3(NB_*NH_*(NT_/128)), dim3(256), 0, stream>>>(qb, kb, vb, yb);
  // 4) out = y @ w_proj + b_proj (f32); 384 blocks, all resident
  gemmP<<<dim3(384), dim3(256), 0, stream>>>(yb, wpt, bp, out);
}